// Round 5
// baseline (958.901 us; speedup 1.0000x reference)
//
#include <hip/hip_runtime.h>
#include <hip/hip_bf16.h>
#include <math.h>

// Problem constants
#define HD 1024     // hidden H
#define ID 512      // moe intermediate I
#define NE 32       // n experts
#define NT 2048     // tokens T = B*S
#define NG 4        // n_group
#define SHI 1024    // shared intermediate I*N_SHARED
#define SCALE 2.5f

#define BK 32
#define LDA 40      // LDS row stride in bf16 elems (80 B rows; 2-way bank aliasing only)
#define BN 64       // (fallback path tile)

typedef __bf16 bf16_t;
typedef __attribute__((ext_vector_type(8))) __bf16 bf16x8;
typedef __attribute__((ext_vector_type(4))) __bf16 bf16x4;
typedef __attribute__((ext_vector_type(4))) float f32x4;

__device__ inline bf16x4 cvt4(float4 v) {
    bf16x4 r;
    r[0] = (__bf16)v.x; r[1] = (__bf16)v.y; r[2] = (__bf16)v.z; r[3] = (__bf16)v.w;
    return r;
}

// ---------------- router stage 1: logits GEMM + zero counts + zero out ----------------
#define LTOK 8
#define LKC 64
__global__ void __launch_bounds__(256) logits_kernel(
    const float* __restrict__ hs, const float* __restrict__ rw,
    float* __restrict__ logits, int* __restrict__ counts,
    float* __restrict__ outz)
{
    int tid = threadIdx.x;
    if (blockIdx.x == 0 && tid < NE) counts[tid] = 0;

    // zero-fill out: 256 blocks x 256 thr x 32 floats = NT*HD
    {
        size_t base = ((size_t)blockIdx.x * 256 + tid) * 32;
        float4 z = {0.f, 0.f, 0.f, 0.f};
        float4* p = (float4*)(outz + base);
        #pragma unroll
        for (int i = 0; i < 8; ++i) p[i] = z;
    }

    __shared__ float Xs[LTOK][68];
    __shared__ float Ws[NE][65];

    int t0 = blockIdx.x * LTOK;
    int tslot = tid >> 5, ecol = tid & 31;
    float acc = 0.f;

    for (int k0 = 0; k0 < HD; k0 += LKC) {
        if (tid < 128) {
            int row = tid >> 4, q = tid & 15;
            float4 v = *(const float4*)(hs + (size_t)(t0 + row) * HD + k0 + q * 4);
            *(float4*)(&Xs[row][q * 4]) = v;
        }
        #pragma unroll
        for (int i = 0; i < 8; ++i) {
            int idx = i * 256 + tid;
            int e = idx >> 6, kk = idx & 63;
            Ws[e][kk] = rw[(size_t)e * HD + k0 + kk];
        }
        __syncthreads();
        #pragma unroll 8
        for (int kk = 0; kk < LKC; ++kk)
            acc += Xs[tslot][kk] * Ws[ecol][kk];
        __syncthreads();
    }
    logits[(size_t)(t0 + tslot) * NE + ecol] = acc;
}

// ---------------- router stage 2: per-token top-k ----------------
__global__ void __launch_bounds__(256) topk_kernel(
    const float* __restrict__ logits, const float* __restrict__ rb,
    float* __restrict__ topkw, int* __restrict__ counts, int* __restrict__ lists)
{
    int t = blockIdx.x * 256 + threadIdx.x;
    if (t >= NT) return;

    float scores[NE], sfc[NE], tmp[NE];
    #pragma unroll
    for (int e = 0; e < NE; ++e) {
        float l = logits[(size_t)t * NE + e];
        float s = 1.f / (1.f + __expf(-l));
        scores[e] = s;
        sfc[e] = s + rb[e];
    }
    float gs[NG];
    #pragma unroll
    for (int g = 0; g < NG; ++g) {
        float m1 = -1e30f, m2 = -1e30f;
        #pragma unroll
        for (int j = 0; j < 8; ++j) {
            float v = sfc[g * 8 + j];
            if (v > m1) { m2 = m1; m1 = v; } else if (v > m2) m2 = v;
        }
        gs[g] = m1 + m2;
    }
    int g1 = 0;
    #pragma unroll
    for (int g = 1; g < NG; ++g) if (gs[g] > gs[g1]) g1 = g;
    int g2 = -1;
    #pragma unroll
    for (int g = 0; g < NG; ++g) {
        if (g == g1) continue;
        if (g2 < 0 || gs[g] > gs[g2]) g2 = g;
    }
    #pragma unroll
    for (int e = 0; e < NE; ++e) {
        int g = e >> 3;
        tmp[e] = (g == g1 || g == g2) ? sfc[e] : 0.0f;
    }
    int idx[4]; float wk[4]; float wsum = 0.f;
    #pragma unroll
    for (int k = 0; k < 4; ++k) {
        int best = 0; float bv = -1e30f;
        #pragma unroll
        for (int e = 0; e < NE; ++e) if (tmp[e] > bv) { bv = tmp[e]; best = e; }
        idx[k] = best; tmp[best] = -1e30f;
        wk[k] = scores[best]; wsum += wk[k];
    }
    float inv = SCALE / (wsum + 1e-20f);
    #pragma unroll
    for (int k = 0; k < 4; ++k) {
        int p = t * 4 + k;
        topkw[p] = wk[k] * inv;
        int e = idx[k];
        int pos = atomicAdd(&counts[e], 1);
        lists[e * NT + pos] = p;
    }
}

// ======================================================================================
// Direct-fp32 GEMMs: no weight mirrors. Each block owns one (expert, 32-col weight
// slice) and loops M-tiles internally, so its B-slice streams from HBM once and
// re-reads hit L2. Staging: global fp32 -> reg -> cvt -> LDS bf16 (LDA=40 padded),
// double-buffered, one barrier per k-step; next tile's loads issued right after the
// barrier so they overlap compute. 4 waves, each computes 32 rows x 32 cols.
// ======================================================================================

__global__ void __launch_bounds__(256, 3) gateup_f32(
    const float* __restrict__ hs,
    const float* __restrict__ gw, const float* __restrict__ uw,
    const float* __restrict__ sgw, const float* __restrict__ suw,
    bf16_t* __restrict__ hr, bf16_t* __restrict__ hsh,
    const int* __restrict__ lists, const int* __restrict__ counts)
{
    constexpr int BM = 128, NS = HD / BK;   // 32 k-steps
    int bx = blockIdx.x, tid = threadIdx.x;

    int cnt, nb0, ND;
    const float *wg, *wu;
    bf16_t* hout;
    const int* rlist = nullptr;
    if (bx < 512) {                         // routed: e = bx>>4, ntb = bx&15
        int e = bx >> 4; cnt = counts[e];
        nb0 = (bx & 15) * 32;
        wg = gw + (size_t)e * ID * HD;
        wu = uw + (size_t)e * ID * HD;
        hout = hr; ND = ID;
        rlist = lists + e * NT;
    } else {                                // shared: ntb = bx-512 in [0,32)
        cnt = NT; nb0 = (bx - 512) * 32;
        wg = sgw; wu = suw;
        hout = hsh; ND = SHI;
    }

    __shared__ __align__(16) bf16_t As[2][BM * LDA];
    __shared__ __align__(16) bf16_t Bgs[2][32 * LDA];
    __shared__ __align__(16) bf16_t Bus[2][32 * LDA];
    __shared__ int rowid[BM];

    int lane = tid & 63, w = tid >> 6;
    int lrow = lane & 15, quad = lane >> 4;
    int tr = tid >> 3, tc = tid & 7;        // 32 rows x 8 float4-cols

    const float* bgb = wg + (size_t)(nb0 + tr) * HD + tc * 4;
    const float* bub = wu + (size_t)(nb0 + tr) * HD + tc * 4;

    for (int m0 = 0; m0 < cnt; m0 += BM) {
        __syncthreads();                    // seal LDS/rowid from previous m-tile
        if (tid < BM) {
            int gm = m0 + tid;
            int mm = gm < cnt ? gm : cnt - 1;
            rowid[tid] = rlist ? rlist[mm] : mm;
        }
        __syncthreads();

        const float* ab[4];
        #pragma unroll
        for (int rr = 0; rr < 4; ++rr) {
            int row = rr * 32 + tr;
            int tok = rlist ? (rowid[row] >> 2) : rowid[row];
            ab[rr] = hs + (size_t)tok * HD + tc * 4;
        }

        f32x4 accg[2][2], accu[2][2];
        #pragma unroll
        for (int i = 0; i < 2; ++i)
            #pragma unroll
            for (int j = 0; j < 2; ++j) { accg[i][j] = (f32x4){0,0,0,0}; accu[i][j] = (f32x4){0,0,0,0}; }

        float4 a[4], bgq, buq;
        #pragma unroll
        for (int rr = 0; rr < 4; ++rr) a[rr] = *(const float4*)(ab[rr]);
        bgq = *(const float4*)(bgb);
        buq = *(const float4*)(bub);

        for (int ks = 0; ks < NS; ++ks) {
            int buf = ks & 1;
            // commit tile ks (implicit vmcnt wait on a/bgq/buq)
            #pragma unroll
            for (int rr = 0; rr < 4; ++rr)
                *(bf16x4*)(&As[buf][(rr * 32 + tr) * LDA + tc * 4]) = cvt4(a[rr]);
            *(bf16x4*)(&Bgs[buf][tr * LDA + tc * 4]) = cvt4(bgq);
            *(bf16x4*)(&Bus[buf][tr * LDA + tc * 4]) = cvt4(buq);
            __syncthreads();
            // issue tile ks+1 loads (overlap with compute below)
            if (ks + 1 < NS) {
                int k = (ks + 1) * BK;
                #pragma unroll
                for (int rr = 0; rr < 4; ++rr) a[rr] = *(const float4*)(ab[rr] + k);
                bgq = *(const float4*)(bgb + k);
                buq = *(const float4*)(bub + k);
            }
            // compute tile ks
            bf16x8 af[2], bgf[2], buf_[2];
            #pragma unroll
            for (int mt = 0; mt < 2; ++mt)
                af[mt] = *(const bf16x8*)(&As[buf][(w * 32 + mt * 16 + lrow) * LDA + quad * 8]);
            #pragma unroll
            for (int nt = 0; nt < 2; ++nt) {
                bgf[nt]  = *(const bf16x8*)(&Bgs[buf][(nt * 16 + lrow) * LDA + quad * 8]);
                buf_[nt] = *(const bf16x8*)(&Bus[buf][(nt * 16 + lrow) * LDA + quad * 8]);
            }
            #pragma unroll
            for (int mt = 0; mt < 2; ++mt)
                #pragma unroll
                for (int nt = 0; nt < 2; ++nt) {
                    accg[mt][nt] = __builtin_amdgcn_mfma_f32_16x16x32_bf16(af[mt], bgf[nt],  accg[mt][nt], 0, 0, 0);
                    accu[mt][nt] = __builtin_amdgcn_mfma_f32_16x16x32_bf16(af[mt], buf_[nt], accu[mt][nt], 0, 0, 0);
                }
        }

        // epilogue: h = silu(g)*u
        #pragma unroll
        for (int mt = 0; mt < 2; ++mt)
            #pragma unroll
            for (int r = 0; r < 4; ++r) {
                int row_local = w * 32 + mt * 16 + quad * 4 + r;
                int gm = m0 + row_local;
                if (gm >= cnt) continue;
                int p = rowid[row_local];
                #pragma unroll
                for (int nt = 0; nt < 2; ++nt) {
                    int col = nb0 + nt * 16 + lrow;
                    float gv = accg[mt][nt][r], uv = accu[mt][nt][r];
                    float h = (gv / (1.f + __expf(-gv))) * uv;
                    hout[(size_t)p * ND + col] = (__bf16)h;
                }
            }
    }
}

__global__ void __launch_bounds__(256, 3) down_f32(
    const bf16_t* __restrict__ hr, const bf16_t* __restrict__ hsh,
    const float* __restrict__ dwf, const float* __restrict__ sdwf,
    float* __restrict__ out,
    const int* __restrict__ lists, const int* __restrict__ counts,
    const float* __restrict__ topkw)
{
    constexpr int BM = 128;
    int bx = blockIdx.x, tid = threadIdx.x;

    int cnt, nb0, KD;
    const bf16_t* Hin;
    const float* wd;
    const int* rlist = nullptr;
    bool routed;
    if (bx < 1024) {                        // routed: e = bx>>5, ntb = bx&31
        int e = bx >> 5; cnt = counts[e];
        nb0 = (bx & 31) * 32;
        Hin = hr; wd = dwf + (size_t)e * HD * ID; KD = ID;
        rlist = lists + e * NT; routed = true;
    } else {                                // shared: ntb = bx-1024 in [0,32)
        cnt = NT; nb0 = (bx - 1024) * 32;
        Hin = hsh; wd = sdwf; KD = SHI; routed = false;
    }
    int NS = KD / BK;                       // 16 or 32

    __shared__ __align__(16) bf16_t As[2][BM * LDA];
    __shared__ __align__(16) bf16_t Ws[2][32 * LDA];
    __shared__ int rowid[BM];

    int lane = tid & 63, w = tid >> 6;
    int lrow = lane & 15, quad = lane >> 4;
    int tr = tid >> 3, tc = tid & 7;

    const float* wb = wd + (size_t)(nb0 + tr) * KD + tc * 4;

    for (int m0 = 0; m0 < cnt; m0 += BM) {
        __syncthreads();
        if (tid < BM) {
            int gm = m0 + tid;
            int mm = gm < cnt ? gm : cnt - 1;
            rowid[tid] = rlist ? rlist[mm] : mm;
        }
        __syncthreads();

        // A chunk mapping: 128 rows x 4 chunks of 16B (32 bf16/row)
        const bf16_t* ab[2];
        int arow_[2], ach_[2];
        #pragma unroll
        for (int rr = 0; rr < 2; ++rr) {
            int idx = rr * 256 + tid;
            arow_[rr] = idx >> 2; ach_[rr] = idx & 3;
            ab[rr] = Hin + (size_t)rowid[arow_[rr]] * KD + ach_[rr] * 8;
        }

        f32x4 acc[2][2];
        #pragma unroll
        for (int i = 0; i < 2; ++i)
            #pragma unroll
            for (int j = 0; j < 2; ++j) acc[i][j] = (f32x4){0,0,0,0};

        bf16x8 a2[2]; float4 wq;
        #pragma unroll
        for (int rr = 0; rr < 2; ++rr) a2[rr] = *(const bf16x8*)(ab[rr]);
        wq = *(const float4*)(wb);

        for (int ks = 0; ks < NS; ++ks) {
            int buf = ks & 1;
            #pragma unroll
            for (int rr = 0; rr < 2; ++rr)
                *(bf16x8*)(&As[buf][arow_[rr] * LDA + ach_[rr] * 8]) = a2[rr];
            *(bf16x4*)(&Ws[buf][tr * LDA + tc * 4]) = cvt4(wq);
            __syncthreads();
            if (ks + 1 < NS) {
                int k = (ks + 1) * BK;
                #pragma unroll
                for (int rr = 0; rr < 2; ++rr) a2[rr] = *(const bf16x8*)(ab[rr] + k);
                wq = *(const float4*)(wb + k);
            }
            bf16x8 af[2], wf[2];
            #pragma unroll
            for (int mt = 0; mt < 2; ++mt)
                af[mt] = *(const bf16x8*)(&As[buf][(w * 32 + mt * 16 + lrow) * LDA + quad * 8]);
            #pragma unroll
            for (int nt = 0; nt < 2; ++nt)
                wf[nt] = *(const bf16x8*)(&Ws[buf][(nt * 16 + lrow) * LDA + quad * 8]);
            #pragma unroll
            for (int mt = 0; mt < 2; ++mt)
                #pragma unroll
                for (int nt = 0; nt < 2; ++nt)
                    acc[mt][nt] = __builtin_amdgcn_mfma_f32_16x16x32_bf16(af[mt], wf[nt], acc[mt][nt], 0, 0, 0);
        }

        #pragma unroll
        for (int mt = 0; mt < 2; ++mt)
            #pragma unroll
            for (int r = 0; r < 4; ++r) {
                int row_local = w * 32 + mt * 16 + quad * 4 + r;
                int gm = m0 + row_local;
                if (gm >= cnt) continue;
                int p = rowid[row_local];
                #pragma unroll
                for (int nt = 0; nt < 2; ++nt) {
                    int col = nb0 + nt * 16 + lrow;
                    float val = acc[mt][nt][r];
                    if (routed) {
                        atomicAdd(&out[(size_t)(p >> 2) * HD + col], topkw[p] * val);
                    } else {
                        atomicAdd(&out[(size_t)p * HD + col], val);
                    }
                }
            }
    }
}

// ======================================================================================
// OLD PATH (fallback when workspace too small) — known-passing code
// ======================================================================================

template<bool EXPERT, int ND, int BMT>
__global__ void __launch_bounds__(256) gateup_mfma(
    const float* __restrict__ X, const float* __restrict__ Wg,
    const float* __restrict__ Wu, bf16_t* __restrict__ Hout,
    const int* __restrict__ lists, const int* __restrict__ counts)
{
    int e = 0, cnt = NT;
    const float* wg = Wg; const float* wu = Wu;
    if (EXPERT) {
        e = blockIdx.x; cnt = counts[e];
        wg = Wg + (size_t)e * ND * HD;
        wu = Wu + (size_t)e * ND * HD;
    }
    int mtb = blockIdx.y, ntb = blockIdx.z;
    if (mtb * BMT >= cnt) return;

    __shared__ __align__(16) bf16_t As[BMT * LDA];
    __shared__ __align__(16) bf16_t Bgs[BN * LDA];
    __shared__ __align__(16) bf16_t Bus[BN * LDA];
    __shared__ int rowid[BMT];

    int tid = threadIdx.x;
    if (tid < BMT) {
        int gm = mtb * BMT + tid;
        int mm = gm < cnt ? gm : cnt - 1;
        rowid[tid] = EXPERT ? lists[e * NT + mm] : mm;
    }
    __syncthreads();

    constexpr int AR = (BMT * BK) / (256 * 4);
    constexpr int BR = (BN * BK) / (256 * 4);
    constexpr int MT = BMT / 32;

    int lane = tid & 63;
    int w = tid >> 6;
    int wm = w & 1, wn = w >> 1;
    int lrow = lane & 15, quad = lane >> 4;

    f32x4 accg[MT][2], accu[MT][2];
    #pragma unroll
    for (int i = 0; i < MT; ++i)
        #pragma unroll
        for (int j = 0; j < 2; ++j) { accg[i][j] = (f32x4){0,0,0,0}; accu[i][j] = (f32x4){0,0,0,0}; }

    float4 pa[AR], pbg[BR], pbu[BR];

    #pragma unroll
    for (int r = 0; r < AR; ++r) {
        int idx = r * 256 + tid;
        int row = idx >> 3, kq = idx & 7;
        int tok = EXPERT ? (rowid[row] >> 2) : rowid[row];
        pa[r] = *(const float4*)(X + (size_t)tok * HD + kq * 4);
    }
    #pragma unroll
    for (int r = 0; r < BR; ++r) {
        int idx = r * 256 + tid;
        int n = idx >> 3, kq = idx & 7;
        size_t off = (size_t)(ntb * BN + n) * HD + kq * 4;
        pbg[r] = *(const float4*)(wg + off);
        pbu[r] = *(const float4*)(wu + off);
    }

    for (int k0 = 0; k0 < HD; k0 += BK) {
        #pragma unroll
        for (int r = 0; r < AR; ++r) {
            int idx = r * 256 + tid;
            int row = idx >> 3, kq = idx & 7;
            *(bf16x4*)(As + row * LDA + kq * 4) = cvt4(pa[r]);
        }
        #pragma unroll
        for (int r = 0; r < BR; ++r) {
            int idx = r * 256 + tid;
            int n = idx >> 3, kq = idx & 7;
            *(bf16x4*)(Bgs + n * LDA + kq * 4) = cvt4(pbg[r]);
            *(bf16x4*)(Bus + n * LDA + kq * 4) = cvt4(pbu[r]);
        }
        __syncthreads();

        int k1 = k0 + BK;
        if (k1 < HD) {
            #pragma unroll
            for (int r = 0; r < AR; ++r) {
                int idx = r * 256 + tid;
                int row = idx >> 3, kq = idx & 7;
                int tok = EXPERT ? (rowid[row] >> 2) : rowid[row];
                pa[r] = *(const float4*)(X + (size_t)tok * HD + k1 + kq * 4);
            }
            #pragma unroll
            for (int r = 0; r < BR; ++r) {
                int idx = r * 256 + tid;
                int n = idx >> 3, kq = idx & 7;
                size_t off = (size_t)(ntb * BN + n) * HD + k1 + kq * 4;
                pbg[r] = *(const float4*)(wg + off);
                pbu[r] = *(const float4*)(wu + off);
            }
        }

        bf16x8 af[MT], bg[2], bu[2];
        #pragma unroll
        for (int mt = 0; mt < MT; ++mt)
            af[mt] = *(const bf16x8*)(As + (wm * (BMT / 2) + mt * 16 + lrow) * LDA + quad * 8);
        #pragma unroll
        for (int nt = 0; nt < 2; ++nt) {
            bg[nt] = *(const bf16x8*)(Bgs + (wn * 32 + nt * 16 + lrow) * LDA + quad * 8);
            bu[nt] = *(const bf16x8*)(Bus + (wn * 32 + nt * 16 + lrow) * LDA + quad * 8);
        }
        #pragma unroll
        for (int mt = 0; mt < MT; ++mt)
            #pragma unroll
            for (int nt = 0; nt < 2; ++nt) {
                accg[mt][nt] = __builtin_amdgcn_mfma_f32_16x16x32_bf16(af[mt], bg[nt], accg[mt][nt], 0, 0, 0);
                accu[mt][nt] = __builtin_amdgcn_mfma_f32_16x16x32_bf16(af[mt], bu[nt], accu[mt][nt], 0, 0, 0);
            }
        __syncthreads();
    }

    #pragma unroll
    for (int mt = 0; mt < MT; ++mt)
        #pragma unroll
        for (int r = 0; r < 4; ++r) {
            int row_local = wm * (BMT / 2) + mt * 16 + quad * 4 + r;
            int gm = mtb * BMT + row_local;
            if (gm >= cnt) continue;
            int p = rowid[row_local];
            #pragma unroll
            for (int nt = 0; nt < 2; ++nt) {
                int col = ntb * BN + wn * 32 + nt * 16 + lrow;
                float g = accg[mt][nt][r], u = accu[mt][nt][r];
                float h = (g / (1.f + __expf(-g))) * u;
                Hout[(size_t)p * ND + col] = (__bf16)h;
            }
        }
}

template<bool EXPERT, int KD, int BMT>
__global__ void __launch_bounds__(256) down_mfma(
    const bf16_t* __restrict__ Hin, const float* __restrict__ Wd,
    float* __restrict__ out, const int* __restrict__ lists,
    const int* __restrict__ counts, const float* __restrict__ topkw)
{
    int e = 0, cnt = NT;
    const float* wd = Wd;
    if (EXPERT) {
        e = blockIdx.x; cnt = counts[e];
        wd = Wd + (size_t)e * HD * KD;
    }
    int mtb = blockIdx.y, ntb = blockIdx.z;
    if (mtb * BMT >= cnt) return;

    __shared__ __align__(16) bf16_t As[BMT * LDA];
    __shared__ __align__(16) bf16_t Ws[BN * LDA];
    __shared__ int rowid[BMT];

    int tid = threadIdx.x;
    if (tid < BMT) {
        int gm = mtb * BMT + tid;
        int mm = gm < cnt ? gm : cnt - 1;
        rowid[tid] = EXPERT ? lists[e * NT + mm] : mm;
    }
    __syncthreads();

    constexpr int ARH = (BMT * BK / 8) / 256;
    constexpr int BR = (BN * BK) / (256 * 4);
    constexpr int MT = BMT / 32;

    int lane = tid & 63;
    int w = tid >> 6;
    int wm = w & 1, wn = w >> 1;
    int lrow = lane & 15, quad = lane >> 4;

    f32x4 acc[MT][2];
    #pragma unroll
    for (int i = 0; i < MT; ++i)
        #pragma unroll
        for (int j = 0; j < 2; ++j) acc[i][j] = (f32x4){0,0,0,0};

    bf16x8 pa[ARH];
    float4 pw[BR];

    #pragma unroll
    for (int r = 0; r < ARH; ++r) {
        int idx = r * 256 + tid;
        int row = idx >> 2, c = idx & 3;
        pa[r] = *(const bf16x8*)(Hin + (size_t)rowid[row] * KD + c * 8);
    }
    #pragma unroll
    for (int r = 0; r < BR; ++r) {
        int idx = r * 256 + tid;
        int n = idx >> 3, kq = idx & 7;
        pw[r] = *(const float4*)(wd + (size_t)(ntb * BN + n) * KD + kq * 4);
    }

    for (int k0 = 0; k0 < KD; k0 += BK) {
        #pragma unroll
        for (int r = 0; r < ARH; ++r) {
            int idx = r * 256 + tid;
            int row = idx >> 2, c = idx & 3;
            *(bf16x8*)(As + row * LDA + c * 8) = pa[r];
        }
        #pragma unroll
        for (int r = 0; r < BR; ++r) {
            int idx = r * 256 + tid;
            int n = idx >> 3, kq = idx & 7;
            *(bf16x4*)(Ws + n * LDA + kq * 4) = cvt4(pw[r]);
        }
        __syncthreads();

        int k1 = k0 + BK;
        if (k1 < KD) {
            #pragma unroll
            for (int r = 0; r < ARH; ++r) {
                int idx = r * 256 + tid;
                int row = idx >> 2, c = idx & 3;
                pa[r] = *(const bf16x8*)(Hin + (size_t)rowid[row] * KD + k1 + c * 8);
            }
            #pragma unroll
            for (int r = 0; r < BR; ++r) {
                int idx = r * 256 + tid;
                int n = idx >> 3, kq = idx & 7;
                pw[r] = *(const float4*)(wd + (size_t)(ntb * BN + n) * KD + k1 + kq * 4);
            }
        }

        bf16x8 af[MT], bfr[2];
        #pragma unroll
        for (int mt = 0; mt < MT; ++mt)
            af[mt] = *(const bf16x8*)(As + (wm * (BMT / 2) + mt * 16 + lrow) * LDA + quad * 8);
        #pragma unroll
        for (int nt = 0; nt < 2; ++nt)
            bfr[nt] = *(const bf16x8*)(Ws + (wn * 32 + nt * 16 + lrow) * LDA + quad * 8);
        #pragma unroll
        for (int mt = 0; mt < MT; ++mt)
            #pragma unroll
            for (int nt = 0; nt < 2; ++nt)
                acc[mt][nt] = __builtin_amdgcn_mfma_f32_16x16x32_bf16(af[mt], bfr[nt], acc[mt][nt], 0, 0, 0);
        __syncthreads();
    }

    #pragma unroll
    for (int mt = 0; mt < MT; ++mt)
        #pragma unroll
        for (int r = 0; r < 4; ++r) {
            int row_local = wm * (BMT / 2) + mt * 16 + quad * 4 + r;
            int gm = mtb * BMT + row_local;
            if (gm >= cnt) continue;
            int p = rowid[row_local];
            #pragma unroll
            for (int nt = 0; nt < 2; ++nt) {
                int col = ntb * BN + wn * 32 + nt * 16 + lrow;
                float val = acc[mt][nt][r];
                if (EXPERT) {
                    float wgt = topkw[p];
                    atomicAdd(&out[(size_t)(p >> 2) * HD + col], wgt * val);
                } else {
                    out[(size_t)p * HD + col] = val;
                }
            }
        }
}

extern "C" void kernel_launch(void* const* d_in, const int* in_sizes, int n_in,
                              void* d_out, int out_size, void* d_ws, size_t ws_size,
                              hipStream_t stream) {
    const float* hs  = (const float*)d_in[0];
    const float* rw  = (const float*)d_in[1];
    const float* rb  = (const float*)d_in[2];
    const float* gw  = (const float*)d_in[3];
    const float* uw  = (const float*)d_in[4];
    const float* dw  = (const float*)d_in[5];
    const float* sgw = (const float*)d_in[6];
    const float* suw = (const float*)d_in[7];
    const float* sdw = (const float*)d_in[8];
    float* out = (float*)d_out;
    char* ws = (char*)d_ws;

    constexpr size_t HR_B  = (size_t)NT * 4 * ID * 2;   // 8 MB
    constexpr size_t HSH_B = (size_t)NT * SHI * 2;      // 4 MB
    constexpr size_t REQ_WS = (size_t)(1 << 20) + HR_B + HSH_B;

    if (ws_size >= REQ_WS) {
        // ---- direct-fp32 path ----
        int*    counts = (int*)ws;
        float*  topkw  = (float*)(ws + 1024);
        int*    lists  = (int*)(ws + 1024 + 32768);
        float*  logits = (float*)(ws + 1024 + 32768 + 262144);
        bf16_t* hr     = (bf16_t*)(ws + (1 << 20));
        bf16_t* hsh    = (bf16_t*)(ws + (1 << 20) + HR_B);

        logits_kernel<<<NT / LTOK, 256, 0, stream>>>(hs, rw, logits, counts, out);
        topk_kernel<<<NT / 256, 256, 0, stream>>>(logits, rb, topkw, counts, lists);
        gateup_f32<<<544, 256, 0, stream>>>(hs, gw, uw, sgw, suw, hr, hsh, lists, counts);
        down_f32<<<1056, 256, 0, stream>>>(hr, hsh, dw, sdw, out, lists, counts, topkw);
    } else {
        // ---- fallback: original known-good path ----
        int*    counts = (int*)ws;
        float*  topkw  = (float*)(ws + 128);
        int*    lists  = (int*)(ws + 128 + 32768);
        float*  logits = (float*)(ws + 128 + 32768 + 262144);
        bf16_t* hbuf   = (bf16_t*)(ws + 128 + 32768 + 262144 + 262144);

        logits_kernel<<<NT / LTOK, 256, 0, stream>>>(hs, rw, logits, counts, out);
        topk_kernel<<<NT / 256, 256, 0, stream>>>(logits, rb, topkw, counts, lists);

        gateup_mfma<false, SHI, 64><<<dim3(1, NT / 64, SHI / BN), 256, 0, stream>>>(
            hs, sgw, suw, hbuf, nullptr, nullptr);
        down_mfma<false, SHI, 64><<<dim3(1, NT / 64, HD / BN), 256, 0, stream>>>(
            hbuf, sdw, out, nullptr, nullptr, nullptr);

        gateup_mfma<true, ID, 128><<<dim3(NE, NT / 128, ID / BN), 256, 0, stream>>>(
            hs, gw, uw, hbuf, lists, counts);
        down_mfma<true, ID, 128><<<dim3(NE, NT / 128, HD / BN), 256, 0, stream>>>(
            hbuf, dw, out, lists, counts, topkw);
    }
}

// Round 6
// 365.945 us; speedup vs baseline: 2.6203x; 2.6203x over previous
//
#include <hip/hip_runtime.h>
#include <hip/hip_bf16.h>
#include <math.h>

// Problem constants
#define HD 1024     // hidden H
#define ID 512      // moe intermediate I
#define NE 32       // n experts
#define NT 2048     // tokens T = B*S
#define NG 4        // n_group
#define SHI 1024    // shared intermediate I*N_SHARED
#define SCALE 2.5f

#define BK 32
#define LDA 40      // LDS row stride in bf16 elems (80B rows; 2-way bank aliasing only)
#define BN 64

typedef __bf16 bf16_t;
typedef __attribute__((ext_vector_type(8))) __bf16 bf16x8;
typedef __attribute__((ext_vector_type(4))) __bf16 bf16x4;
typedef __attribute__((ext_vector_type(4))) float f32x4;

__device__ inline bf16x4 cvt4(float4 v) {
    bf16x4 r;
    r[0] = (__bf16)v.x; r[1] = (__bf16)v.y; r[2] = (__bf16)v.z; r[3] = (__bf16)v.w;
    return r;
}

// ---------------- router stage 1: logits GEMM + zero counts ----------------
#define LTOK 8
#define LKC 64
__global__ void __launch_bounds__(256) logits_kernel(
    const float* __restrict__ hs, const float* __restrict__ rw,
    float* __restrict__ logits, int* __restrict__ counts)
{
    int tid = threadIdx.x;
    if (blockIdx.x == 0 && tid < NE) counts[tid] = 0;

    __shared__ float Xs[LTOK][68];
    __shared__ float Ws[NE][65];

    int t0 = blockIdx.x * LTOK;
    int tslot = tid >> 5, ecol = tid & 31;
    float acc = 0.f;

    for (int k0 = 0; k0 < HD; k0 += LKC) {
        if (tid < 128) {
            int row = tid >> 4, q = tid & 15;
            float4 v = *(const float4*)(hs + (size_t)(t0 + row) * HD + k0 + q * 4);
            *(float4*)(&Xs[row][q * 4]) = v;
        }
        #pragma unroll
        for (int i = 0; i < 8; ++i) {
            int idx = i * 256 + tid;
            int e = idx >> 6, kk = idx & 63;
            Ws[e][kk] = rw[(size_t)e * HD + k0 + kk];
        }
        __syncthreads();
        #pragma unroll 8
        for (int kk = 0; kk < LKC; ++kk)
            acc += Xs[tslot][kk] * Ws[ecol][kk];
        __syncthreads();
    }
    logits[(size_t)(t0 + tslot) * NE + ecol] = acc;
}

// ---------------- router stage 2: per-token top-k ----------------
__global__ void __launch_bounds__(256) topk_kernel(
    const float* __restrict__ logits, const float* __restrict__ rb,
    float* __restrict__ topkw, int* __restrict__ counts, int* __restrict__ lists)
{
    int t = blockIdx.x * 256 + threadIdx.x;
    if (t >= NT) return;

    float scores[NE], sfc[NE], tmp[NE];
    #pragma unroll
    for (int e = 0; e < NE; ++e) {
        float l = logits[(size_t)t * NE + e];
        float s = 1.f / (1.f + __expf(-l));
        scores[e] = s;
        sfc[e] = s + rb[e];
    }
    float gs[NG];
    #pragma unroll
    for (int g = 0; g < NG; ++g) {
        float m1 = -1e30f, m2 = -1e30f;
        #pragma unroll
        for (int j = 0; j < 8; ++j) {
            float v = sfc[g * 8 + j];
            if (v > m1) { m2 = m1; m1 = v; } else if (v > m2) m2 = v;
        }
        gs[g] = m1 + m2;
    }
    int g1 = 0;
    #pragma unroll
    for (int g = 1; g < NG; ++g) if (gs[g] > gs[g1]) g1 = g;
    int g2 = -1;
    #pragma unroll
    for (int g = 0; g < NG; ++g) {
        if (g == g1) continue;
        if (g2 < 0 || gs[g] > gs[g2]) g2 = g;
    }
    #pragma unroll
    for (int e = 0; e < NE; ++e) {
        int g = e >> 3;
        tmp[e] = (g == g1 || g == g2) ? sfc[e] : 0.0f;
    }
    int idx[4]; float wk[4]; float wsum = 0.f;
    #pragma unroll
    for (int k = 0; k < 4; ++k) {
        int best = 0; float bv = -1e30f;
        #pragma unroll
        for (int e = 0; e < NE; ++e) if (tmp[e] > bv) { bv = tmp[e]; best = e; }
        idx[k] = best; tmp[best] = -1e30f;
        wk[k] = scores[best]; wsum += wk[k];
    }
    float inv = SCALE / (wsum + 1e-20f);
    #pragma unroll
    for (int k = 0; k < 4; ++k) {
        int p = t * 4 + k;
        topkw[p] = wk[k] * inv;
        int e = idx[k];
        int pos = atomicAdd(&counts[e], 1);
        lists[e * NT + pos] = p;
    }
}

// ======================================================================================
// FUSED direct-fp32 GEMMs (round-0 proven internals + round-2 role fusion, no mirrors).
// Reg-staged fp32 -> cvt -> LDS bf16 (LDA=40), single LDS buffer, 2 barriers/k-step,
// next tile's global loads issued right after barrier (overlap with compute).
// Grid (33, ntb(y,fast), mtb(z,slow)): blocks sharing A-rows adjacent in dispatch
// order -> A re-reads hit L2. bx<32 routed expert e=bx; bx==32 shared.
// ======================================================================================

__global__ void __launch_bounds__(256) gateup_all2(
    const float* __restrict__ hs,
    const float* __restrict__ gw, const float* __restrict__ uw,
    const float* __restrict__ sgw, const float* __restrict__ suw,
    bf16_t* __restrict__ hr, bf16_t* __restrict__ hsh,
    const int* __restrict__ lists, const int* __restrict__ counts)
{
    constexpr int BMT = 128, MT = 4;
    int bx = blockIdx.x, ntb = blockIdx.y, mtb = blockIdx.z;
    int tid = threadIdx.x;

    int cnt, ND;
    const float *wg, *wu;
    bf16_t* hout;
    const int* rlist = nullptr;
    if (bx < 32) {
        int e = bx; cnt = counts[e];
        if (ntb >= 8) return;                 // routed: ID/BN = 8 col-tiles
        if (mtb * BMT >= cnt) return;
        wg = gw + (size_t)e * ID * HD;
        wu = uw + (size_t)e * ID * HD;
        hout = hr; ND = ID;
        rlist = lists + e * NT;
    } else {
        cnt = NT;                             // shared: 16 col-tiles x 16 m-tiles
        wg = sgw; wu = suw;
        hout = hsh; ND = SHI;
    }

    __shared__ __align__(16) bf16_t As[BMT * LDA];
    __shared__ __align__(16) bf16_t Bgs[BN * LDA];
    __shared__ __align__(16) bf16_t Bus[BN * LDA];
    __shared__ int rowid[BMT];

    if (tid < BMT) {
        int gm = mtb * BMT + tid;
        int mm = gm < cnt ? gm : cnt - 1;
        rowid[tid] = rlist ? rlist[mm] : mm;
    }
    __syncthreads();

    constexpr int AR = (BMT * BK) / (256 * 4);   // 4
    constexpr int BR = (BN * BK) / (256 * 4);    // 2

    int lane = tid & 63;
    int w = tid >> 6;
    int wm = w & 1, wn = w >> 1;
    int lrow = lane & 15, quad = lane >> 4;

    f32x4 accg[MT][2], accu[MT][2];
    #pragma unroll
    for (int i = 0; i < MT; ++i)
        #pragma unroll
        for (int j = 0; j < 2; ++j) { accg[i][j] = (f32x4){0,0,0,0}; accu[i][j] = (f32x4){0,0,0,0}; }

    float4 pa[AR], pbg[BR], pbu[BR];

    #pragma unroll
    for (int r = 0; r < AR; ++r) {
        int idx = r * 256 + tid;
        int row = idx >> 3, kq = idx & 7;
        int tok = rlist ? (rowid[row] >> 2) : rowid[row];
        pa[r] = *(const float4*)(hs + (size_t)tok * HD + kq * 4);
    }
    #pragma unroll
    for (int r = 0; r < BR; ++r) {
        int idx = r * 256 + tid;
        int n = idx >> 3, kq = idx & 7;
        size_t off = (size_t)(ntb * BN + n) * HD + kq * 4;
        pbg[r] = *(const float4*)(wg + off);
        pbu[r] = *(const float4*)(wu + off);
    }

    for (int k0 = 0; k0 < HD; k0 += BK) {
        #pragma unroll
        for (int r = 0; r < AR; ++r) {
            int idx = r * 256 + tid;
            int row = idx >> 3, kq = idx & 7;
            *(bf16x4*)(As + row * LDA + kq * 4) = cvt4(pa[r]);
        }
        #pragma unroll
        for (int r = 0; r < BR; ++r) {
            int idx = r * 256 + tid;
            int n = idx >> 3, kq = idx & 7;
            *(bf16x4*)(Bgs + n * LDA + kq * 4) = cvt4(pbg[r]);
            *(bf16x4*)(Bus + n * LDA + kq * 4) = cvt4(pbu[r]);
        }
        __syncthreads();

        int k1 = k0 + BK;
        if (k1 < HD) {
            #pragma unroll
            for (int r = 0; r < AR; ++r) {
                int idx = r * 256 + tid;
                int row = idx >> 3, kq = idx & 7;
                int tok = rlist ? (rowid[row] >> 2) : rowid[row];
                pa[r] = *(const float4*)(hs + (size_t)tok * HD + k1 + kq * 4);
            }
            #pragma unroll
            for (int r = 0; r < BR; ++r) {
                int idx = r * 256 + tid;
                int n = idx >> 3, kq = idx & 7;
                size_t off = (size_t)(ntb * BN + n) * HD + k1 + kq * 4;
                pbg[r] = *(const float4*)(wg + off);
                pbu[r] = *(const float4*)(wu + off);
            }
        }

        bf16x8 af[MT], bg[2], bu[2];
        #pragma unroll
        for (int mt = 0; mt < MT; ++mt)
            af[mt] = *(const bf16x8*)(As + (wm * (BMT / 2) + mt * 16 + lrow) * LDA + quad * 8);
        #pragma unroll
        for (int nt = 0; nt < 2; ++nt) {
            bg[nt] = *(const bf16x8*)(Bgs + (wn * 32 + nt * 16 + lrow) * LDA + quad * 8);
            bu[nt] = *(const bf16x8*)(Bus + (wn * 32 + nt * 16 + lrow) * LDA + quad * 8);
        }
        #pragma unroll
        for (int mt = 0; mt < MT; ++mt)
            #pragma unroll
            for (int nt = 0; nt < 2; ++nt) {
                accg[mt][nt] = __builtin_amdgcn_mfma_f32_16x16x32_bf16(af[mt], bg[nt], accg[mt][nt], 0, 0, 0);
                accu[mt][nt] = __builtin_amdgcn_mfma_f32_16x16x32_bf16(af[mt], bu[nt], accu[mt][nt], 0, 0, 0);
            }
        __syncthreads();
    }

    #pragma unroll
    for (int mt = 0; mt < MT; ++mt)
        #pragma unroll
        for (int r = 0; r < 4; ++r) {
            int row_local = wm * (BMT / 2) + mt * 16 + quad * 4 + r;
            int gm = mtb * BMT + row_local;
            if (gm >= cnt) continue;
            int p = rowid[row_local];
            #pragma unroll
            for (int nt = 0; nt < 2; ++nt) {
                int col = ntb * BN + wn * 32 + nt * 16 + lrow;
                float gv = accg[mt][nt][r], uv = accu[mt][nt][r];
                float h = (gv / (1.f + __expf(-gv))) * uv;
                hout[(size_t)p * ND + col] = (__bf16)h;
            }
        }
}

// Down projection: plain stores (no atomics). Routed writes topkw[p]*val into
// slotbuf[p][col] (each slot+col owned by exactly one thread); shared writes shsum.
__global__ void __launch_bounds__(256) down_all2(
    const bf16_t* __restrict__ hr, const bf16_t* __restrict__ hsh,
    const float* __restrict__ dwf, const float* __restrict__ sdwf,
    float* __restrict__ slotbuf, float* __restrict__ shsum,
    const int* __restrict__ lists, const int* __restrict__ counts,
    const float* __restrict__ topkw)
{
    constexpr int BMT = 128, MT = 4;
    int bx = blockIdx.x, ntb = blockIdx.y, mtb = blockIdx.z;
    int tid = threadIdx.x;

    int cnt, KD;
    const bf16_t* Hin;
    const float* wd;
    const int* rlist = nullptr;
    bool routed;
    if (bx < 32) {
        int e = bx; cnt = counts[e];
        if (mtb * BMT >= cnt) return;
        Hin = hr; wd = dwf + (size_t)e * HD * ID; KD = ID;
        rlist = lists + e * NT; routed = true;
    } else {
        cnt = NT;
        Hin = hsh; wd = sdwf; KD = SHI; routed = false;
    }
    int NS = KD / BK;   // 16 or 32

    __shared__ __align__(16) bf16_t As[BMT * LDA];
    __shared__ __align__(16) bf16_t Ws[BN * LDA];
    __shared__ int rowid[BMT];

    if (tid < BMT) {
        int gm = mtb * BMT + tid;
        int mm = gm < cnt ? gm : cnt - 1;
        rowid[tid] = rlist ? rlist[mm] : mm;
    }
    __syncthreads();

    constexpr int ARH = (BMT * BK / 8) / 256;   // 2
    constexpr int BR = (BN * BK) / (256 * 4);   // 2

    int lane = tid & 63;
    int w = tid >> 6;
    int wm = w & 1, wn = w >> 1;
    int lrow = lane & 15, quad = lane >> 4;

    f32x4 acc[MT][2];
    #pragma unroll
    for (int i = 0; i < MT; ++i)
        #pragma unroll
        for (int j = 0; j < 2; ++j) acc[i][j] = (f32x4){0,0,0,0};

    bf16x8 pa[ARH];
    float4 pw[BR];

    #pragma unroll
    for (int r = 0; r < ARH; ++r) {
        int idx = r * 256 + tid;
        int row = idx >> 2, c = idx & 3;
        pa[r] = *(const bf16x8*)(Hin + (size_t)rowid[row] * KD + c * 8);
    }
    #pragma unroll
    for (int r = 0; r < BR; ++r) {
        int idx = r * 256 + tid;
        int n = idx >> 3, kq = idx & 7;
        pw[r] = *(const float4*)(wd + (size_t)(ntb * BN + n) * KD + kq * 4);
    }

    for (int ks = 0; ks < NS; ++ks) {
        #pragma unroll
        for (int r = 0; r < ARH; ++r) {
            int idx = r * 256 + tid;
            int row = idx >> 2, c = idx & 3;
            *(bf16x8*)(As + row * LDA + c * 8) = pa[r];
        }
        #pragma unroll
        for (int r = 0; r < BR; ++r) {
            int idx = r * 256 + tid;
            int n = idx >> 3, kq = idx & 7;
            *(bf16x4*)(Ws + n * LDA + kq * 4) = cvt4(pw[r]);
        }
        __syncthreads();

        if (ks + 1 < NS) {
            int k1 = (ks + 1) * BK;
            #pragma unroll
            for (int r = 0; r < ARH; ++r) {
                int idx = r * 256 + tid;
                int row = idx >> 2, c = idx & 3;
                pa[r] = *(const bf16x8*)(Hin + (size_t)rowid[row] * KD + k1 + c * 8);
            }
            #pragma unroll
            for (int r = 0; r < BR; ++r) {
                int idx = r * 256 + tid;
                int n = idx >> 3, kq = idx & 7;
                pw[r] = *(const float4*)(wd + (size_t)(ntb * BN + n) * KD + k1 + kq * 4);
            }
        }

        bf16x8 af[MT], bfr[2];
        #pragma unroll
        for (int mt = 0; mt < MT; ++mt)
            af[mt] = *(const bf16x8*)(As + (wm * (BMT / 2) + mt * 16 + lrow) * LDA + quad * 8);
        #pragma unroll
        for (int nt = 0; nt < 2; ++nt)
            bfr[nt] = *(const bf16x8*)(Ws + (wn * 32 + nt * 16 + lrow) * LDA + quad * 8);
        #pragma unroll
        for (int mt = 0; mt < MT; ++mt)
            #pragma unroll
            for (int nt = 0; nt < 2; ++nt)
                acc[mt][nt] = __builtin_amdgcn_mfma_f32_16x16x32_bf16(af[mt], bfr[nt], acc[mt][nt], 0, 0, 0);
        __syncthreads();
    }

    #pragma unroll
    for (int mt = 0; mt < MT; ++mt)
        #pragma unroll
        for (int r = 0; r < 4; ++r) {
            int row_local = wm * (BMT / 2) + mt * 16 + quad * 4 + r;
            int gm = mtb * BMT + row_local;
            if (gm >= cnt) continue;
            int p = rowid[row_local];
            #pragma unroll
            for (int nt = 0; nt < 2; ++nt) {
                int col = ntb * BN + wn * 32 + nt * 16 + lrow;
                float val = acc[mt][nt][r];
                if (routed) {
                    slotbuf[(size_t)p * HD + col] = topkw[p] * val;
                } else {
                    shsum[(size_t)p * HD + col] = val;
                }
            }
        }
}

// out[t][c] = sum_k slotbuf[t*4+k][c] + shsum[t][c]
__global__ void __launch_bounds__(256) finalize_kernel(
    const float* __restrict__ slotbuf, const float* __restrict__ shsum,
    float* __restrict__ out)
{
    int i = blockIdx.x * 256 + threadIdx.x;   // over NT*HD/4
    int t = i >> 8;                           // 256 float4 per row
    int c4 = i & 255;
    const float4* s0 = (const float4*)(slotbuf + (size_t)(t * 4 + 0) * HD) + c4;
    const float4* s1 = (const float4*)(slotbuf + (size_t)(t * 4 + 1) * HD) + c4;
    const float4* s2 = (const float4*)(slotbuf + (size_t)(t * 4 + 2) * HD) + c4;
    const float4* s3 = (const float4*)(slotbuf + (size_t)(t * 4 + 3) * HD) + c4;
    const float4* sh = (const float4*)(shsum + (size_t)t * HD) + c4;
    float4 a = *s0, b = *s1, c = *s2, d = *s3, e = *sh;
    float4 o;
    o.x = a.x + b.x + c.x + d.x + e.x;
    o.y = a.y + b.y + c.y + d.y + e.y;
    o.z = a.z + b.z + c.z + d.z + e.z;
    o.w = a.w + b.w + c.w + d.w + e.w;
    ((float4*)(out + (size_t)t * HD))[c4] = o;
}

// ======================================================================================
// FALLBACK (small workspace): round-0 known-good path
// ======================================================================================

template<bool EXPERT, int ND, int BMT>
__global__ void __launch_bounds__(256) gateup_mfma(
    const float* __restrict__ X, const float* __restrict__ Wg,
    const float* __restrict__ Wu, bf16_t* __restrict__ Hout,
    const int* __restrict__ lists, const int* __restrict__ counts)
{
    int e = 0, cnt = NT;
    const float* wg = Wg; const float* wu = Wu;
    if (EXPERT) {
        e = blockIdx.x; cnt = counts[e];
        wg = Wg + (size_t)e * ND * HD;
        wu = Wu + (size_t)e * ND * HD;
    }
    int mtb = blockIdx.y, ntb = blockIdx.z;
    if (mtb * BMT >= cnt) return;

    __shared__ __align__(16) bf16_t As[BMT * LDA];
    __shared__ __align__(16) bf16_t Bgs[BN * LDA];
    __shared__ __align__(16) bf16_t Bus[BN * LDA];
    __shared__ int rowid[BMT];

    int tid = threadIdx.x;
    if (tid < BMT) {
        int gm = mtb * BMT + tid;
        int mm = gm < cnt ? gm : cnt - 1;
        rowid[tid] = EXPERT ? lists[e * NT + mm] : mm;
    }
    __syncthreads();

    constexpr int AR = (BMT * BK) / (256 * 4);
    constexpr int BR = (BN * BK) / (256 * 4);
    constexpr int MT = BMT / 32;

    int lane = tid & 63;
    int w = tid >> 6;
    int wm = w & 1, wn = w >> 1;
    int lrow = lane & 15, quad = lane >> 4;

    f32x4 accg[MT][2], accu[MT][2];
    #pragma unroll
    for (int i = 0; i < MT; ++i)
        #pragma unroll
        for (int j = 0; j < 2; ++j) { accg[i][j] = (f32x4){0,0,0,0}; accu[i][j] = (f32x4){0,0,0,0}; }

    float4 pa[AR], pbg[BR], pbu[BR];

    #pragma unroll
    for (int r = 0; r < AR; ++r) {
        int idx = r * 256 + tid;
        int row = idx >> 3, kq = idx & 7;
        int tok = EXPERT ? (rowid[row] >> 2) : rowid[row];
        pa[r] = *(const float4*)(X + (size_t)tok * HD + kq * 4);
    }
    #pragma unroll
    for (int r = 0; r < BR; ++r) {
        int idx = r * 256 + tid;
        int n = idx >> 3, kq = idx & 7;
        size_t off = (size_t)(ntb * BN + n) * HD + kq * 4;
        pbg[r] = *(const float4*)(wg + off);
        pbu[r] = *(const float4*)(wu + off);
    }

    for (int k0 = 0; k0 < HD; k0 += BK) {
        #pragma unroll
        for (int r = 0; r < AR; ++r) {
            int idx = r * 256 + tid;
            int row = idx >> 3, kq = idx & 7;
            *(bf16x4*)(As + row * LDA + kq * 4) = cvt4(pa[r]);
        }
        #pragma unroll
        for (int r = 0; r < BR; ++r) {
            int idx = r * 256 + tid;
            int n = idx >> 3, kq = idx & 7;
            *(bf16x4*)(Bgs + n * LDA + kq * 4) = cvt4(pbg[r]);
            *(bf16x4*)(Bus + n * LDA + kq * 4) = cvt4(pbu[r]);
        }
        __syncthreads();

        int k1 = k0 + BK;
        if (k1 < HD) {
            #pragma unroll
            for (int r = 0; r < AR; ++r) {
                int idx = r * 256 + tid;
                int row = idx >> 3, kq = idx & 7;
                int tok = EXPERT ? (rowid[row] >> 2) : rowid[row];
                pa[r] = *(const float4*)(X + (size_t)tok * HD + k1 + kq * 4);
            }
            #pragma unroll
            for (int r = 0; r < BR; ++r) {
                int idx = r * 256 + tid;
                int n = idx >> 3, kq = idx & 7;
                size_t off = (size_t)(ntb * BN + n) * HD + k1 + kq * 4;
                pbg[r] = *(const float4*)(wg + off);
                pbu[r] = *(const float4*)(wu + off);
            }
        }

        bf16x8 af[MT], bg[2], bu[2];
        #pragma unroll
        for (int mt = 0; mt < MT; ++mt)
            af[mt] = *(const bf16x8*)(As + (wm * (BMT / 2) + mt * 16 + lrow) * LDA + quad * 8);
        #pragma unroll
        for (int nt = 0; nt < 2; ++nt) {
            bg[nt] = *(const bf16x8*)(Bgs + (wn * 32 + nt * 16 + lrow) * LDA + quad * 8);
            bu[nt] = *(const bf16x8*)(Bus + (wn * 32 + nt * 16 + lrow) * LDA + quad * 8);
        }
        #pragma unroll
        for (int mt = 0; mt < MT; ++mt)
            #pragma unroll
            for (int nt = 0; nt < 2; ++nt) {
                accg[mt][nt] = __builtin_amdgcn_mfma_f32_16x16x32_bf16(af[mt], bg[nt], accg[mt][nt], 0, 0, 0);
                accu[mt][nt] = __builtin_amdgcn_mfma_f32_16x16x32_bf16(af[mt], bu[nt], accu[mt][nt], 0, 0, 0);
            }
        __syncthreads();
    }

    #pragma unroll
    for (int mt = 0; mt < MT; ++mt)
        #pragma unroll
        for (int r = 0; r < 4; ++r) {
            int row_local = wm * (BMT / 2) + mt * 16 + quad * 4 + r;
            int gm = mtb * BMT + row_local;
            if (gm >= cnt) continue;
            int p = rowid[row_local];
            #pragma unroll
            for (int nt = 0; nt < 2; ++nt) {
                int col = ntb * BN + wn * 32 + nt * 16 + lrow;
                float g = accg[mt][nt][r], u = accu[mt][nt][r];
                float h = (g / (1.f + __expf(-g))) * u;
                Hout[(size_t)p * ND + col] = (__bf16)h;
            }
        }
}

template<bool EXPERT, int KD, int BMT>
__global__ void __launch_bounds__(256) down_mfma(
    const bf16_t* __restrict__ Hin, const float* __restrict__ Wd,
    float* __restrict__ out, const int* __restrict__ lists,
    const int* __restrict__ counts, const float* __restrict__ topkw)
{
    int e = 0, cnt = NT;
    const float* wd = Wd;
    if (EXPERT) {
        e = blockIdx.x; cnt = counts[e];
        wd = Wd + (size_t)e * HD * KD;
    }
    int mtb = blockIdx.y, ntb = blockIdx.z;
    if (mtb * BMT >= cnt) return;

    __shared__ __align__(16) bf16_t As[BMT * LDA];
    __shared__ __align__(16) bf16_t Ws[BN * LDA];
    __shared__ int rowid[BMT];

    int tid = threadIdx.x;
    if (tid < BMT) {
        int gm = mtb * BMT + tid;
        int mm = gm < cnt ? gm : cnt - 1;
        rowid[tid] = EXPERT ? lists[e * NT + mm] : mm;
    }
    __syncthreads();

    constexpr int ARH = (BMT * BK / 8) / 256;
    constexpr int BR = (BN * BK) / (256 * 4);
    constexpr int MT = BMT / 32;

    int lane = tid & 63;
    int w = tid >> 6;
    int wm = w & 1, wn = w >> 1;
    int lrow = lane & 15, quad = lane >> 4;

    f32x4 acc[MT][2];
    #pragma unroll
    for (int i = 0; i < MT; ++i)
        #pragma unroll
        for (int j = 0; j < 2; ++j) acc[i][j] = (f32x4){0,0,0,0};

    bf16x8 pa[ARH];
    float4 pw[BR];

    #pragma unroll
    for (int r = 0; r < ARH; ++r) {
        int idx = r * 256 + tid;
        int row = idx >> 2, c = idx & 3;
        pa[r] = *(const bf16x8*)(Hin + (size_t)rowid[row] * KD + c * 8);
    }
    #pragma unroll
    for (int r = 0; r < BR; ++r) {
        int idx = r * 256 + tid;
        int n = idx >> 3, kq = idx & 7;
        pw[r] = *(const float4*)(wd + (size_t)(ntb * BN + n) * KD + kq * 4);
    }

    for (int k0 = 0; k0 < KD; k0 += BK) {
        #pragma unroll
        for (int r = 0; r < ARH; ++r) {
            int idx = r * 256 + tid;
            int row = idx >> 2, c = idx & 3;
            *(bf16x8*)(As + row * LDA + c * 8) = pa[r];
        }
        #pragma unroll
        for (int r = 0; r < BR; ++r) {
            int idx = r * 256 + tid;
            int n = idx >> 3, kq = idx & 7;
            *(bf16x4*)(Ws + n * LDA + kq * 4) = cvt4(pw[r]);
        }
        __syncthreads();

        int k1 = k0 + BK;
        if (k1 < KD) {
            #pragma unroll
            for (int r = 0; r < ARH; ++r) {
                int idx = r * 256 + tid;
                int row = idx >> 2, c = idx & 3;
                pa[r] = *(const bf16x8*)(Hin + (size_t)rowid[row] * KD + k1 + c * 8);
            }
            #pragma unroll
            for (int r = 0; r < BR; ++r) {
                int idx = r * 256 + tid;
                int n = idx >> 3, kq = idx & 7;
                pw[r] = *(const float4*)(wd + (size_t)(ntb * BN + n) * KD + k1 + kq * 4);
            }
        }

        bf16x8 af[MT], bfr[2];
        #pragma unroll
        for (int mt = 0; mt < MT; ++mt)
            af[mt] = *(const bf16x8*)(As + (wm * (BMT / 2) + mt * 16 + lrow) * LDA + quad * 8);
        #pragma unroll
        for (int nt = 0; nt < 2; ++nt)
            bfr[nt] = *(const bf16x8*)(Ws + (wn * 32 + nt * 16 + lrow) * LDA + quad * 8);
        #pragma unroll
        for (int mt = 0; mt < MT; ++mt)
            #pragma unroll
            for (int nt = 0; nt < 2; ++nt)
                acc[mt][nt] = __builtin_amdgcn_mfma_f32_16x16x32_bf16(af[mt], bfr[nt], acc[mt][nt], 0, 0, 0);
        __syncthreads();
    }

    #pragma unroll
    for (int mt = 0; mt < MT; ++mt)
        #pragma unroll
        for (int r = 0; r < 4; ++r) {
            int row_local = wm * (BMT / 2) + mt * 16 + quad * 4 + r;
            int gm = mtb * BMT + row_local;
            if (gm >= cnt) continue;
            int p = rowid[row_local];
            #pragma unroll
            for (int nt = 0; nt < 2; ++nt) {
                int col = ntb * BN + wn * 32 + nt * 16 + lrow;
                float val = acc[mt][nt][r];
                if (EXPERT) {
                    float wgt = topkw[p];
                    atomicAdd(&out[(size_t)(p >> 2) * HD + col], wgt * val);
                } else {
                    out[(size_t)p * HD + col] = val;
                }
            }
        }
}

extern "C" void kernel_launch(void* const* d_in, const int* in_sizes, int n_in,
                              void* d_out, int out_size, void* d_ws, size_t ws_size,
                              hipStream_t stream) {
    const float* hs  = (const float*)d_in[0];
    const float* rw  = (const float*)d_in[1];
    const float* rb  = (const float*)d_in[2];
    const float* gw  = (const float*)d_in[3];
    const float* uw  = (const float*)d_in[4];
    const float* dw  = (const float*)d_in[5];
    const float* sgw = (const float*)d_in[6];
    const float* suw = (const float*)d_in[7];
    const float* sdw = (const float*)d_in[8];
    float* out = (float*)d_out;
    char* ws = (char*)d_ws;

    constexpr size_t HR_B   = (size_t)NT * 4 * ID * 2;      // 8 MB  (bf16)
    constexpr size_t HSH_B  = (size_t)NT * SHI * 2;         // 4 MB  (bf16)
    constexpr size_t SLOT_B = (size_t)NT * 4 * HD * 4;      // 32 MB (fp32)
    constexpr size_t SHS_B  = (size_t)NT * HD * 4;          // 8 MB  (fp32)
    constexpr size_t REQ_WS = (size_t)(1 << 20) + HR_B + HSH_B + SLOT_B + SHS_B;

    if (ws_size >= REQ_WS) {
        // ---- fused direct-fp32 path, no atomics ----
        int*    counts  = (int*)ws;
        float*  topkw   = (float*)(ws + 1024);
        int*    lists   = (int*)(ws + 1024 + 32768);
        float*  logits  = (float*)(ws + 1024 + 32768 + 262144);
        bf16_t* hr      = (bf16_t*)(ws + (1 << 20));
        bf16_t* hsh     = (bf16_t*)(ws + (1 << 20) + HR_B);
        float*  slotbuf = (float*)(ws + (1 << 20) + HR_B + HSH_B);
        float*  shsum   = (float*)(ws + (1 << 20) + HR_B + HSH_B + SLOT_B);

        logits_kernel<<<NT / LTOK, 256, 0, stream>>>(hs, rw, logits, counts);
        topk_kernel<<<NT / 256, 256, 0, stream>>>(logits, rb, topkw, counts, lists);
        gateup_all2<<<dim3(33, 16, 16), 256, 0, stream>>>(
            hs, gw, uw, sgw, suw, hr, hsh, lists, counts);
        down_all2<<<dim3(33, 16, 16), 256, 0, stream>>>(
            hr, hsh, dw, sdw, slotbuf, shsum, lists, counts, topkw);
        finalize_kernel<<<(NT * HD / 4) / 256, 256, 0, stream>>>(slotbuf, shsum, out);
    } else {
        // ---- fallback: round-0 known-good path ----
        int*    counts = (int*)ws;
        float*  topkw  = (float*)(ws + 128);
        int*    lists  = (int*)(ws + 128 + 32768);
        float*  logits = (float*)(ws + 128 + 32768 + 262144);
        bf16_t* hbuf   = (bf16_t*)(ws + 128 + 32768 + 262144 + 262144);

        logits_kernel<<<NT / LTOK, 256, 0, stream>>>(hs, rw, logits, counts);
        topk_kernel<<<NT / 256, 256, 0, stream>>>(logits, rb, topkw, counts, lists);

        gateup_mfma<false, SHI, 64><<<dim3(1, NT / 64, SHI / BN), 256, 0, stream>>>(
            hs, sgw, suw, hbuf, nullptr, nullptr);
        down_mfma<false, SHI, 64><<<dim3(1, NT / 64, HD / BN), 256, 0, stream>>>(
            hbuf, sdw, out, nullptr, nullptr, nullptr);

        gateup_mfma<true, ID, 128><<<dim3(NE, NT / 128, ID / BN), 256, 0, stream>>>(
            hs, gw, uw, hbuf, lists, counts);
        down_mfma<true, ID, 128><<<dim3(NE, NT / 128, HD / BN), 256, 0, stream>>>(
            hbuf, dw, out, lists, counts, topkw);
    }
}